// Round 10
// baseline (136.511 us; speedup 1.0000x reference)
//
#include <hip/hip_runtime.h>
#include <hip/hip_bf16.h>
#include <math.h>

// Problem constants (from reference)
#define B_ 8
#define T_ 1024
#define D_ 256
#define K_ 100
#define G_ 2
#define V_ 320
#define NT_ 101            // 1 positive + K negatives
#define TEMP_ 0.1f
#define DIV_W_ 0.1f
#define L2_W_ 10.0f
#define DIV_EPS_ 1e-7f
#define COS_EPS_ 1e-8f

// ws float layout
#define WS_AVG   2          // 640 avg-prob accumulators
#define WS_FLAG  643        // mask-layout flag (int)
#define WS_SSQ   644        // 512 per-block ssq partials (norm blocks)
#define WS_ZERO_TOP WS_SSQ  // memset range [0, WS_SSQ)
#define WS_LOSSP 17408      // 8192 per-block loss partials (plain stores)
#define WS_QBF16 25600      // bf16 copy of quant: 8192 rows x 512 B = 4 MB
#define WS_BF16_BYTES ((size_t)(WS_QBF16 + (size_t)B_ * T_ * D_ / 2) * 4)

#define NORM_BLOCKS 512
#define CB_BLOCKS   256

__device__ inline unsigned short f2bf_rne(float f) {
    unsigned int u = __float_as_uint(f);
    u += 0x7FFFu + ((u >> 16) & 1u);
    return (unsigned short)(u >> 16);
}

// ---------------------------------------------------------------------------
// Prep: blocks [0,512) = batch-affine quant pack (bf16) + ssq partials
// (block 0 also detects mask layout); blocks [512,768) = codebook softmax
// accumulation (nontemporal). Pack blocks use the same b = blk&7 mapping as
// contrastive, pre-warming each XCD's L2 with the batch it gathers later.
// No norms are precomputed anymore -- contrastive derives them on the fly.
// ---------------------------------------------------------------------------
template <bool PACK_BF16>
__global__ __launch_bounds__(256) void prep_kernel(
    const float* __restrict__ q, const float* __restrict__ cb,
    const unsigned int* __restrict__ maskw, float* __restrict__ ws)
{
    __shared__ float sh[G_ * V_];
    __shared__ int sA, sB;
    const int tid = threadIdx.x;
    const int lane = tid & 63;
    const int wavein = tid >> 6;
    const int blk = blockIdx.x;

    if (blk < NORM_BLOCKS) {
        const int b = blk & 7;             // XCD affinity (blockIdx % 8)
        const int seg = blk >> 3;          // 0..63 : 16 rows each
        float ssq = 0.0f;
#pragma unroll
        for (int i = 0; i < 4; i++) {
            const int r = b * T_ + seg * 16 + wavein * 4 + i;
            const float4 v = ((const float4*)(q + (size_t)r * D_))[lane];
            ssq += v.x * v.x + v.y * v.y + v.z * v.z + v.w * v.w;
            if (PACK_BF16) {
                ushort4 pk;
                pk.x = f2bf_rne(v.x); pk.y = f2bf_rne(v.y);
                pk.z = f2bf_rne(v.z); pk.w = f2bf_rne(v.w);
                ((ushort4*)((char*)ws + (size_t)WS_QBF16 * 4 +
                            (size_t)r * 512))[lane] = pk;
            }
        }
#pragma unroll
        for (int sft = 32; sft >= 1; sft >>= 1) ssq += __shfl_xor(ssq, sft);
        if (lane == 0) sh[wavein] = ssq;
        __syncthreads();
        if (tid == 0)
            ws[WS_SSQ + blk] = sh[0] + sh[1] + sh[2] + sh[3];

        if (blk == 0) {
            if (tid == 0) { sA = 0; sB = 0; }
            __syncthreads();
            int a = 0, bb = 0;
            for (int i = tid; i < (B_ * T_) / 4; i += 256) {
                const unsigned int w = maskw[i];
                a  |= (w > 1u) ? 1 : 0;
                bb |= (w != 0u && w != 0x3F800000u) ? 1 : 0;
            }
            if (a)  atomicOr(&sA, 1);
            if (bb) atomicOr(&sB, 1);
            __syncthreads();
            if (tid == 0)
                ((int*)ws)[WS_FLAG] = (!sA) ? 0 : ((!sB) ? 1 : 2);
        }
    } else {
        // ---------------- codebook diversity path ----------------
        for (int i = tid; i < G_ * V_; i += 256) sh[i] = 0.0f;
        __syncthreads();
        const int cblk = blk - NORM_BLOCKS;       // 0..255
        const int base = cblk * 4 + wavein;       // 0..1023
        float r0[5] = {0, 0, 0, 0, 0};
        float r1[5] = {0, 0, 0, 0, 0};
        const bool odd = (base & 1);
#pragma unroll 1
        for (int i = 0; i < 16; i++) {
            const int r = base + 1024 * i;        // parity constant per wave
            const float* row = cb + (size_t)r * V_;
            float v[5];
#pragma unroll
            for (int j = 0; j < 5; j++)
                v[j] = __builtin_nontemporal_load(&row[lane + 64 * j]);
            float mx = fmaxf(fmaxf(fmaxf(v[0], v[1]), fmaxf(v[2], v[3])), v[4]);
#pragma unroll
            for (int s = 32; s >= 1; s >>= 1) mx = fmaxf(mx, __shfl_xor(mx, s));
            float e[5], sum = 0.0f;
#pragma unroll
            for (int j = 0; j < 5; j++) { e[j] = __expf(v[j] - mx); sum += e[j]; }
#pragma unroll
            for (int s = 32; s >= 1; s >>= 1) sum += __shfl_xor(sum, s);
            const float is = 1.0f / sum;
            if (odd) {
#pragma unroll
                for (int j = 0; j < 5; j++) r1[j] += e[j] * is;
            } else {
#pragma unroll
                for (int j = 0; j < 5; j++) r0[j] += e[j] * is;
            }
        }
#pragma unroll
        for (int j = 0; j < 5; j++) {
            atomicAdd(&sh[0 * V_ + lane + 64 * j], r0[j]);
            atomicAdd(&sh[1 * V_ + lane + 64 * j], r1[j]);
        }
        __syncthreads();
        for (int i = tid; i < G_ * V_; i += 256)
            atomicAdd(&ws[WS_AVG + i], sh[i]);
    }
}

// ---------------------------------------------------------------------------
// Contrastive: one block per (b,t), b = blk&7 XCD affinity. Wave 0 loads the
// pred row and reduces its norm while waves 1-2 load the indices (concurrent,
// single barrier). Gather loop computes dot AND target-norm on the fly from
// the same loaded row (no norm precompute). Per-block result: plain store.
// ---------------------------------------------------------------------------
template <bool USE_BF16>
__global__ __launch_bounds__(256) void contrastive_kernel(
    const float* __restrict__ quant,
    const float* __restrict__ ctx,
    const int* __restrict__ negidx,
    const void* __restrict__ maskp,
    float* __restrict__ ws)
{
    const int cblk = blockIdx.x;
    const int b = cblk & 7;                  // batch -> XCD affinity
    const int t = cblk >> 3;
    const int bt = b * T_ + t;

    const int tid = threadIdx.x;
    const int flag = ((const int*)ws)[WS_FLAG];
    bool m;
    if (flag == 2)      m = ((const unsigned char*)maskp)[bt] != 0;
    else if (flag == 1) m = ((const float*)maskp)[bt] != 0.0f;
    else                m = ((const int*)maskp)[bt] != 0;
    if (!m) {                                // block-uniform
        if (tid == 0) ws[WS_LOSSP + cblk] = 0.0f;
        return;
    }

    __shared__ float s_pred[D_];             // 1 KB
    __shared__ float s_pn;
    __shared__ int   s_idx[NT_ + 3];
    __shared__ float s_logit[NT_ + 3];

    // concurrent phase-1: wave 0 -> pred + its norm; waves 1-2 -> indices
    if (tid < 64) {
        const float4 v = ((const float4*)(ctx + (size_t)bt * D_))[tid];
        ((float4*)s_pred)[tid] = v;
        float s = v.x * v.x + v.y * v.y + v.z * v.z + v.w * v.w;
#pragma unroll
        for (int sh = 32; sh >= 1; sh >>= 1) s += __shfl_xor(s, sh);
        if (tid == 0) s_pn = sqrtf(s);
    } else if (tid < 64 + K_) {
        s_idx[tid - 63] =
            __builtin_nontemporal_load(&negidx[(size_t)bt * K_ + (tid - 64)]);
    } else if (tid == 64 + K_) {
        s_idx[0] = t;
    }
    __syncthreads();

    const float pn = s_pn;
    const int g = tid >> 2;                  // 0..63
    const int p = tid & 3;

#pragma unroll
    for (int pass = 0; pass < 2; ++pass) {
        const int k = g + 64 * pass;
        if (k < NT_) {
            const int idx = s_idx[k];
            float dot = 0.0f, tn2 = 0.0f;
            if (USE_BF16) {
                const uint4* row = (const uint4*)((const char*)ws +
                    (size_t)WS_QBF16 * 4 + (size_t)(b * T_ + idx) * 512);
                uint4 u[8];
#pragma unroll
                for (int i = 0; i < 8; ++i) u[i] = row[i * 4 + p];
#pragma unroll
                for (int i = 0; i < 8; ++i) {
                    const int J0 = (p + 4 * i) * 4;   // float2 index in row
                    const unsigned int w0 = u[i].x, w1 = u[i].y,
                                       w2 = u[i].z, w3 = u[i].w;
                    const float2 q0 = ((const float2*)s_pred)[J0 + 0];
                    const float2 q1 = ((const float2*)s_pred)[J0 + 1];
                    const float2 q2 = ((const float2*)s_pred)[J0 + 2];
                    const float2 q3 = ((const float2*)s_pred)[J0 + 3];
                    const float a0 = __uint_as_float(w0 << 16);
                    const float a1 = __uint_as_float(w0 & 0xFFFF0000u);
                    const float a2 = __uint_as_float(w1 << 16);
                    const float a3 = __uint_as_float(w1 & 0xFFFF0000u);
                    const float a4 = __uint_as_float(w2 << 16);
                    const float a5 = __uint_as_float(w2 & 0xFFFF0000u);
                    const float a6 = __uint_as_float(w3 << 16);
                    const float a7 = __uint_as_float(w3 & 0xFFFF0000u);
                    dot += a0 * q0.x + a1 * q0.y + a2 * q1.x + a3 * q1.y
                         + a4 * q2.x + a5 * q2.y + a6 * q3.x + a7 * q3.y;
                    tn2 += a0 * a0 + a1 * a1 + a2 * a2 + a3 * a3
                         + a4 * a4 + a5 * a5 + a6 * a6 + a7 * a7;
                }
            } else {
                const float4* row = (const float4*)(quant +
                    ((size_t)b * T_ + idx) * D_);
                float4 r[16];
#pragma unroll
                for (int i = 0; i < 16; ++i) r[i] = row[i * 4 + p];
#pragma unroll
                for (int i = 0; i < 16; ++i) {
                    const float4 q = ((const float4*)s_pred)[i * 4 + p];
                    dot += r[i].x * q.x + r[i].y * q.y
                         + r[i].z * q.z + r[i].w * q.w;
                    tn2 += r[i].x * r[i].x + r[i].y * r[i].y
                         + r[i].z * r[i].z + r[i].w * r[i].w;
                }
            }
            dot += __shfl_xor(dot, 1);
            dot += __shfl_xor(dot, 2);
            tn2 += __shfl_xor(tn2, 1);
            tn2 += __shfl_xor(tn2, 2);
            if (p == 0) {
                s_logit[k] = (k > 0 && idx == t) ? -1e30f
                    : (dot / fmaxf(pn * sqrtf(tn2), COS_EPS_)) * (1.0f / TEMP_);
            }
        }
    }
    __syncthreads();

    if (tid < 64) {
        const float l0 = s_logit[tid];
        const float l1 = (tid + 64 < NT_) ? s_logit[tid + 64] : -1e30f;
        float mx = fmaxf(l0, l1);
#pragma unroll
        for (int s = 32; s >= 1; s >>= 1) mx = fmaxf(mx, __shfl_xor(mx, s));
        float sum = __expf(l0 - mx) + __expf(l1 - mx);
#pragma unroll
        for (int s = 32; s >= 1; s >>= 1) sum += __shfl_xor(sum, s);
        if (tid == 0) {
            const float logp0 = s_logit[0] - (mx + __logf(sum));
            ws[WS_LOSSP + cblk] = -logp0;    // plain store, no contention
        }
    }
}

// ---------------------------------------------------------------------------
// Finalize (256 thr): sum 8192 loss partials + 512 ssq partials;
// entropy/perplexity; combine.
// ---------------------------------------------------------------------------
__global__ __launch_bounds__(256) void finalize_kernel(
    const float* __restrict__ ws, float* __restrict__ out)
{
    __shared__ float sred[4];
    const int tid = threadIdx.x;
    const int lane = tid & 63;
    const int wavein = tid >> 6;

    float lc = 0.0f;
    for (int i = tid; i < B_ * T_; i += 256) lc += ws[WS_LOSSP + i];
#pragma unroll
    for (int s = 32; s >= 1; s >>= 1) lc += __shfl_xor(lc, s);
    if (lane == 0) sred[wavein] = lc;
    __syncthreads();

    if (tid < 64) {
        float ss = 0.0f;
#pragma unroll
        for (int i = 0; i < 8; i++) ss += ws[WS_SSQ + lane + 64 * i];
        const float* avg = ws + WS_AVG;
        float e0 = 0.0f, e1 = 0.0f;
        const float inv = 1.0f / (float)(B_ * T_);
#pragma unroll
        for (int i = 0; i < 5; i++) {
            const float a0 = avg[0 * V_ + lane + 64 * i] * inv;
            const float a1 = avg[1 * V_ + lane + 64 * i] * inv;
            e0 -= a0 * __logf(a0 + DIV_EPS_);
            e1 -= a1 * __logf(a1 + DIV_EPS_);
        }
#pragma unroll
        for (int s = 32; s >= 1; s >>= 1) {
            ss += __shfl_xor(ss, s);
            e0 += __shfl_xor(e0, s);
            e1 += __shfl_xor(e1, s);
        }
        if (tid == 0) {
            const float loss_c = sred[0] + sred[1] + sred[2] + sred[3];
            const float loss_d = ((float)V_ - __expf(e0)) + ((float)V_ - __expf(e1));
            const float loss_l2 = ss / (float)(B_ * T_ * D_);
            out[0] = loss_c + DIV_W_ * loss_d + L2_W_ * loss_l2;
        }
    }
}

extern "C" void kernel_launch(void* const* d_in, const int* in_sizes, int n_in,
                              void* d_out, int out_size, void* d_ws, size_t ws_size,
                              hipStream_t stream) {
    const float* quant = (const float*)d_in[0];
    const float* ctx   = (const float*)d_in[1];
    const float* cb    = (const float*)d_in[2];
    const int*   nidx  = (const int*)d_in[3];
    const void*  mask  = d_in[4];
    float* ws  = (float*)d_ws;
    float* out = (float*)d_out;

    const bool bf16 = (ws_size >= WS_BF16_BYTES);

    // zero loss/avg accumulators (+flag slot)
    hipMemsetAsync(d_ws, 0, (WS_ZERO_TOP) * sizeof(float), stream);

    if (bf16) {
        prep_kernel<true><<<NORM_BLOCKS + CB_BLOCKS, 256, 0, stream>>>(
            quant, cb, (const unsigned int*)mask, ws);
        contrastive_kernel<true><<<B_ * T_, 256, 0, stream>>>(
            quant, ctx, nidx, mask, ws);
    } else {
        prep_kernel<false><<<NORM_BLOCKS + CB_BLOCKS, 256, 0, stream>>>(
            quant, cb, (const unsigned int*)mask, ws);
        contrastive_kernel<false><<<B_ * T_, 256, 0, stream>>>(
            quant, ctx, nidx, mask, ws);
    }
    finalize_kernel<<<1, 256, 0, stream>>>(ws, out);
}